// Round 3
// baseline (319.892 us; speedup 1.0000x reference)
//
#include <hip/hip_runtime.h>
#include <hip/hip_bf16.h>

// Problem dims (fixed by reference setup)
#define B_   16
#define N_   8
#define C_   512
#define D_   768
#define HH   64
#define WW   64
#define HW   4096          // 64*64 pixels per batch

typedef __bf16 bf16;
typedef __attribute__((ext_vector_type(8))) __bf16 bf16x8;
typedef __attribute__((ext_vector_type(4))) __bf16 bf16x4;
typedef __attribute__((ext_vector_type(4))) float  f32x4;

// ---------------------------------------------------------------------------
// K1a: Q[b,n,c] = sum_d (se[b,n,d]*weights[n]) * wq_w[c,d] + wq_b[c]
__global__ __launch_bounds__(512) void k_q(const float* __restrict__ se,
                                           const float* __restrict__ weights,
                                           const float* __restrict__ wq_w,
                                           const float* __restrict__ wq_b,
                                           float* __restrict__ Q) {
    int bn = blockIdx.x;
    int n  = bn & 7;
    float wt = weights[n];
    const float* we = se + (size_t)bn * D_;
    int c = threadIdx.x;
    const f32x4* wr = (const f32x4*)(wq_w + (size_t)c * D_);
    float acc = wq_b[c];
    #pragma unroll 4
    for (int i = 0; i < D_ / 4; ++i) {
        f32x4 w4 = wr[i];
        acc += (we[4*i+0] * wt) * w4[0];
        acc += (we[4*i+1] * wt) * w4[1];
        acc += (we[4*i+2] * wt) * w4[2];
        acc += (we[4*i+3] * wt) * w4[3];
    }
    Q[(size_t)bn * C_ + c] = acc;
}

// ---------------------------------------------------------------------------
// K1b: Qk[b,n,m] = sum_o Q[b,n,o] * wk_w[o,m]   (wk_b cancels in softmax)
__global__ __launch_bounds__(512) void k_qk(const float* __restrict__ Q,
                                            const float* __restrict__ wk_w,
                                            float* __restrict__ Qk) {
    int bn = blockIdx.x;
    const float* q = Q + (size_t)bn * C_;
    int m = threadIdx.x;
    float acc = 0.f;
    #pragma unroll 8
    for (int o = 0; o < C_; ++o)
        acc = fmaf(q[o], wk_w[(size_t)o * C_ + m], acc);
    Qk[(size_t)bn * C_ + m] = acc;
}

// ---------------------------------------------------------------------------
// K1c: W2[o,c] = sum_m wo_w[o,m]*wv_w[m,c]  (bf16 out);  b2[o] = wo_w[o,:]·wv_b
__global__ __launch_bounds__(512) void k_w2(const float* __restrict__ wo_w,
                                            const float* __restrict__ wv_w,
                                            const float* __restrict__ wv_b,
                                            bf16* __restrict__ W2,
                                            float* __restrict__ b2) {
    int o0 = blockIdx.x * 4;
    int c  = threadIdx.x;
    const float* r0 = wo_w + (size_t)o0 * C_;
    float a0 = 0.f, a1 = 0.f, a2 = 0.f, a3 = 0.f;
    #pragma unroll 8
    for (int m = 0; m < C_; ++m) {
        float v = wv_w[(size_t)m * C_ + c];
        a0 = fmaf(r0[m],          v, a0);
        a1 = fmaf(r0[C_ + m],     v, a1);
        a2 = fmaf(r0[2 * C_ + m], v, a2);
        a3 = fmaf(r0[3 * C_ + m], v, a3);
    }
    W2[(size_t)(o0 + 0) * C_ + c] = (bf16)a0;
    W2[(size_t)(o0 + 1) * C_ + c] = (bf16)a1;
    W2[(size_t)(o0 + 2) * C_ + c] = (bf16)a2;
    W2[(size_t)(o0 + 3) * C_ + c] = (bf16)a3;
    if (c < 4) {
        float sb = 0.f;
        const float* rr = wo_w + (size_t)(o0 + c) * C_;
        #pragma unroll 4
        for (int m = 0; m < C_; ++m) sb = fmaf(rr[m], wv_b[m], sb);
        b2[o0 + c] = sb;
    }
}

// ---------------------------------------------------------------------------
// K2 (fused): per block (b, pt, mt): GEMM acc[o,p] = W2[m-tile]·x[:,p-tile],
// score partials t[n,p] = Qk[n,:]·x[:,p-tile] (f32, from staging regs),
// in-block softmax over w (p-tile = 2 complete h-rows) -> s[p],
// epilogue out = x + wo_b + s*(acc + b2).  x read ONCE; no xT buffer.

__device__ __forceinline__ void gl_lds16(const void* g, void* l) {
    __builtin_amdgcn_global_load_lds(
        (const __attribute__((address_space(1))) void*)g,
        (__attribute__((address_space(3))) void*)l, 16, 0, 0);
}

__global__ __launch_bounds__(256) void k_fused(const float* __restrict__ x,
                                               const bf16* __restrict__ W2,
                                               const float* __restrict__ b2,
                                               const float* __restrict__ wo_b,
                                               const float* __restrict__ Qk,
                                               float* __restrict__ out) {
    // XCD-grouped mapping: the 4 m-tiles of one (b,pt) job land on one XCD,
    // dispatched adjacently -> x pixel-panel (256KB f32) L2 reuse.
    int id = blockIdx.x;
    int xcd = id & 7, chunk = id >> 3;
    int mt = chunk & 3, jrow = chunk >> 2;
    int job = jrow * 8 + xcd;                     // 0..511
    int b = job >> 5, pt = job & 31;
    int m0 = mt * 128;
    int p0 = pt * 128;                            // 2 complete h-rows

    __shared__ __align__(128) unsigned char Al[16384];  // [128 o][64 c] bf16, swizzled
    __shared__ __align__(128) unsigned char Bl[16384];  // [128 p][64 c] bf16, swizzled
    __shared__ float part[2][N_][128];                  // score partials (c-halves)
    __shared__ float att[N_][128];
    __shared__ float s_lds[128];

    int tid = threadIdx.x;
    int wid = tid >> 6, lane = tid & 63;
    int wm = wid >> 1, wn = wid & 1;

    // staging roles: thread owns pixel sp (0..127) and c-half ch (32 c)
    int sp = lane + (wid & 1) * 64;
    int ch = wid >> 1;
    int sw = (sp & 7) << 4;

    float partial[N_] = {};
    f32x4 acc[4][4] = {};

    for (int it = 0; it < 8; ++it) {
        int k0 = it * 64;
        __syncthreads();                          // prev-iter LDS reads done

        // --- A staging: global_load_lds, linear dest + pre-swizzled source ---
        #pragma unroll
        for (int q = 0; q < 4; ++q) {
            int L   = (q * 256 + tid) * 16;       // linear dest byte 0..16K
            int row = L >> 7;                     // 0..127
            int kb  = (L & 127) ^ ((row & 7) << 4);
            gl_lds16(W2 + (size_t)(m0 + row) * C_ + k0 + (kb >> 1), Al + L);
        }

        // --- B staging (reg): f32 loads -> score partials -> bf16 -> LDS ---
        const float* xc = x + ((size_t)b * C_ + k0 + ch * 32) * HW + p0 + sp;
        #pragma unroll
        for (int h = 0; h < 2; ++h) {
            float v[16];
            #pragma unroll
            for (int i = 0; i < 16; ++i)
                v[i] = xc[(size_t)(h * 16 + i) * HW];

            int cb = __builtin_amdgcn_readfirstlane(k0 + ch * 32 + h * 16);
            #pragma unroll
            for (int n = 0; n < N_; ++n) {
                const float* qn = Qk + (size_t)(b * N_ + n) * C_ + cb;  // scalar
                #pragma unroll
                for (int i = 0; i < 16; ++i)
                    partial[n] = fmaf(qn[i], v[i], partial[n]);
            }
            bf16x8 bv0, bv1;
            #pragma unroll
            for (int i = 0; i < 8; ++i) { bv0[i] = (bf16)v[i]; bv1[i] = (bf16)v[8 + i]; }
            int colb = (ch * 32 + h * 16) * 2;    // byte col: 0,32,64,96
            *(bf16x8*)(Bl + sp * 128 + ( colb       ^ sw)) = bv0;
            *(bf16x8*)(Bl + sp * 128 + ((colb + 16) ^ sw)) = bv1;
        }

        __syncthreads();                          // drain vmcnt+lgkm, tiles ready

        // --- MFMA ---
        #pragma unroll
        for (int ks = 0; ks < 2; ++ks) {
            int kb0 = ks * 64 + ((lane >> 4) << 4);
            bf16x8 a[4], bb[4];
            #pragma unroll
            for (int i = 0; i < 4; ++i) {
                int row = wm * 64 + i * 16 + (lane & 15);
                a[i] = *(const bf16x8*)(Al + row * 128 + (kb0 ^ ((row & 7) << 4)));
            }
            #pragma unroll
            for (int j = 0; j < 4; ++j) {
                int row = wn * 64 + j * 16 + (lane & 15);
                bb[j] = *(const bf16x8*)(Bl + row * 128 + (kb0 ^ ((row & 7) << 4)));
            }
            #pragma unroll
            for (int i = 0; i < 4; ++i)
                #pragma unroll
                for (int j = 0; j < 4; ++j)
                    acc[i][j] = __builtin_amdgcn_mfma_f32_16x16x32_bf16(
                                    a[i], bb[j], acc[i][j], 0, 0, 0);
        }
    }

    // --- score reduce + softmax over w (rows of 64) + s[p] ---
    #pragma unroll
    for (int n = 0; n < N_; ++n) part[ch][n][sp] = partial[n];
    __syncthreads();
    #pragma unroll
    for (int nn = 0; nn < 2; ++nn) {
        int n = wid * 2 + nn;                     // 4 waves x 2 = 8 n
        #pragma unroll
        for (int rr = 0; rr < 2; ++rr) {
            int p = rr * 64 + lane;               // lane == w within the row
            float t = (part[0][n][p] + part[1][n][p]) * 3.6084391824351615e-2f;
            float mx = t;
            #pragma unroll
            for (int off = 32; off; off >>= 1) mx = fmaxf(mx, __shfl_xor(mx, off));
            float e = __expf(t - mx);
            float sm = e;
            #pragma unroll
            for (int off = 32; off; off >>= 1) sm += __shfl_xor(sm, off);
            att[n][p] = e / sm;
        }
    }
    __syncthreads();
    if (tid < 128) {
        float sv = 0.f;
        #pragma unroll
        for (int n = 0; n < N_; ++n) sv += att[n][tid];
        s_lds[tid] = sv;
    }
    __syncthreads();

    // --- epilogue: out = x + wo_b + s*(acc + b2); residual from L2-hot x ---
    int r4 = (lane >> 4) << 2;
    int cl = lane & 15;
    #pragma unroll
    for (int j = 0; j < 4; ++j) {
        int pl = wn * 64 + j * 16 + cl;
        float sv = s_lds[pl];
        #pragma unroll
        for (int i = 0; i < 4; ++i) {
            int ob = m0 + wm * 64 + i * 16 + r4;
            f32x4 b2v = *(const f32x4*)(b2 + ob);
            f32x4 wbv = *(const f32x4*)(wo_b + ob);
            #pragma unroll
            for (int r = 0; r < 4; ++r) {
                size_t gi = ((size_t)b * C_ + ob + r) * HW + p0 + pl;
                out[gi] = x[gi] + wbv[r] + sv * (acc[i][j][r] + b2v[r]);
            }
        }
    }
}

// ---------------------------------------------------------------------------
extern "C" void kernel_launch(void* const* d_in, const int* in_sizes, int n_in,
                              void* d_out, int out_size, void* d_ws, size_t ws_size,
                              hipStream_t stream) {
    const float* x    = (const float*)d_in[0];
    const float* se   = (const float*)d_in[1];
    const float* wts  = (const float*)d_in[2];
    const float* wq_w = (const float*)d_in[3];
    const float* wq_b = (const float*)d_in[4];
    const float* wk_w = (const float*)d_in[5];
    // d_in[6] = wk_b: cancels in softmax (constant over w), unused
    const float* wv_w = (const float*)d_in[7];
    const float* wv_b = (const float*)d_in[8];
    const float* wo_w = (const float*)d_in[9];
    const float* wo_b = (const float*)d_in[10];
    float* out = (float*)d_out;

    // workspace layout (~1MB)
    char* ws = (char*)d_ws;
    float* Q   = (float*)(ws + 0);          // 256KB
    float* Qk  = (float*)(ws + 262144);     // 256KB
    bf16*  W2  = (bf16*) (ws + 524288);     // 512KB
    float* b2  = (float*)(ws + 1048576);    // 2KB

    k_q     <<<dim3(128),  dim3(512), 0, stream>>>(se, wts, wq_w, wq_b, Q);
    k_qk    <<<dim3(128),  dim3(512), 0, stream>>>(Q, wk_w, Qk);
    k_w2    <<<dim3(128),  dim3(512), 0, stream>>>(wo_w, wv_w, wv_b, W2, b2);
    k_fused <<<dim3(2048), dim3(256), 0, stream>>>(x, W2, b2, wo_b, Qk, out);
}

// Round 4
// 222.460 us; speedup vs baseline: 1.4380x; 1.4380x over previous
//
#include <hip/hip_runtime.h>
#include <hip/hip_bf16.h>

// Problem dims (fixed by reference setup)
#define B_   16
#define N_   8
#define C_   512
#define D_   768
#define HH   64
#define WW   64
#define HW   4096          // 64*64 pixels per batch

typedef __bf16 bf16;
typedef __attribute__((ext_vector_type(8))) __bf16 bf16x8;
typedef __attribute__((ext_vector_type(4))) __bf16 bf16x4;
typedef __attribute__((ext_vector_type(4))) float  f32x4;

// ---------------------------------------------------------------------------
// K1: fused Q + Qk.  Per block (b, n'): n'<8: Q[c] = wq_b[c] + we·wq_w[c,:]
// (Q in LDS), then Qkb[b,n',m] = bf16( (Q·wk_w[:,m]) / sqrt(768) ).
// Rows n'=8..15 are zero padding (MFMA A-operand wants 16 rows).
__global__ __launch_bounds__(512) void k_qq(const float* __restrict__ se,
                                            const float* __restrict__ weights,
                                            const float* __restrict__ wq_w,
                                            const float* __restrict__ wq_b,
                                            const float* __restrict__ wk_w,
                                            bf16* __restrict__ Qkb) {
    int blk = blockIdx.x;                 // b*16 + n'
    int b = blk >> 4, n = blk & 15;
    int tid = threadIdx.x;
    if (n >= 8) {                         // zero padding rows
        Qkb[(size_t)blk * C_ + tid] = (bf16)0.f;
        return;
    }
    __shared__ float we[D_];
    __shared__ float Q_lds[C_];
    const float* se_row = se + (size_t)(b * N_ + n) * D_;
    float wt = weights[n];
    for (int d = tid; d < D_; d += 512) we[d] = se_row[d] * wt;
    __syncthreads();

    int c = tid;
    const f32x4* wr = (const f32x4*)(wq_w + (size_t)c * D_);
    float acc = wq_b[c];
    #pragma unroll 4
    for (int i = 0; i < D_ / 4; ++i) {
        f32x4 w4 = wr[i];
        acc += we[4*i+0] * w4[0] + we[4*i+1] * w4[1]
             + we[4*i+2] * w4[2] + we[4*i+3] * w4[3];
    }
    Q_lds[c] = acc;
    __syncthreads();

    int m = tid;
    float a2 = 0.f;
    #pragma unroll 8
    for (int o = 0; o < C_; ++o)
        a2 = fmaf(Q_lds[o], wk_w[(size_t)o * C_ + m], a2);
    Qkb[(size_t)blk * C_ + m] = (bf16)(a2 * 3.6084391824351615e-2f);
}

// ---------------------------------------------------------------------------
// K2: W2[o,c] = sum_m wo_w[o,m]*wv_w[m,c]  (bf16 out);  b2[o] = wo_w[o,:]·wv_b
__global__ __launch_bounds__(512) void k_w2(const float* __restrict__ wo_w,
                                            const float* __restrict__ wv_w,
                                            const float* __restrict__ wv_b,
                                            bf16* __restrict__ W2,
                                            float* __restrict__ b2) {
    int o0 = blockIdx.x * 4;
    int c  = threadIdx.x;
    const float* r0 = wo_w + (size_t)o0 * C_;
    float a0 = 0.f, a1 = 0.f, a2 = 0.f, a3 = 0.f;
    #pragma unroll 8
    for (int m = 0; m < C_; ++m) {
        float v = wv_w[(size_t)m * C_ + c];
        a0 = fmaf(r0[m],          v, a0);
        a1 = fmaf(r0[C_ + m],     v, a1);
        a2 = fmaf(r0[2 * C_ + m], v, a2);
        a3 = fmaf(r0[3 * C_ + m], v, a3);
    }
    W2[(size_t)(o0 + 0) * C_ + c] = (bf16)a0;
    W2[(size_t)(o0 + 1) * C_ + c] = (bf16)a1;
    W2[(size_t)(o0 + 2) * C_ + c] = (bf16)a2;
    W2[(size_t)(o0 + 3) * C_ + c] = (bf16)a3;
    if (c < 4) {
        float sb = 0.f;
        const float* rr = wo_w + (size_t)(o0 + c) * C_;
        #pragma unroll 4
        for (int m = 0; m < C_; ++m) sb = fmaf(rr[m], wv_b[m], sb);
        b2[o0 + c] = sb;
    }
}

// ---------------------------------------------------------------------------
// K3 (fused v2): per block (b, pt, mt):
//   GEMM acc[o,p] = W2[m-tile]·x[:,p-tile]      (MFMA, A via global_load_lds)
//   scores t[n,p] = Qkb[n,:]·x[:,p-tile]        (MFMA, shares B fragments)
//   softmax over w (p-tile = 2 complete h-rows) -> s[p]
//   out = x + wo_b + s*(acc + b2)
// B-tile reg-staged f32->bf16->LDS with iter+1 register prefetch.

__device__ __forceinline__ void gl_lds16(const void* g, void* l) {
    __builtin_amdgcn_global_load_lds(
        (const __attribute__((address_space(1))) void*)g,
        (__attribute__((address_space(3))) void*)l, 16, 0, 0);
}

__global__ __launch_bounds__(256, 2) void k_fused(const float* __restrict__ x,
                                                  const bf16* __restrict__ W2,
                                                  const float* __restrict__ b2,
                                                  const float* __restrict__ wo_b,
                                                  const bf16* __restrict__ Qkb,
                                                  float* __restrict__ out) {
    // XCD-grouped mapping: the 4 m-tiles of one (b,pt) job land on one XCD,
    // dispatched adjacently -> x pixel-panel (256KB f32) L2 reuse.
    int id = blockIdx.x;
    int xcd = id & 7, chunk = id >> 3;
    int mt = chunk & 3, jrow = chunk >> 2;
    int job = jrow * 8 + xcd;                     // 0..511
    int b = job >> 5, pt = job & 31;
    int m0 = mt * 128;
    int p0 = pt * 128;                            // 2 complete h-rows

    __shared__ __align__(128) unsigned char Al[16384];  // [128 o][64 c] bf16, swizzled
    __shared__ __align__(128) unsigned char Bl[16384];  // [128 p][64 c] bf16, swizzled
    __shared__ float att[N_][128];
    __shared__ float s_lds[128];

    int tid = threadIdx.x;
    int wid = tid >> 6, lane = tid & 63;
    int wm = wid >> 1, wn = wid & 1;

    // staging roles: thread owns pixel sp (0..127) and c-half ch (32 c)
    int sp = lane + (wid & 1) * 64;
    int ch = wid >> 1;
    int sw = (sp & 7) << 4;

    f32x4 acc[4][4] = {};
    f32x4 acc_q[4] = {};

    // prologue: issue f32 loads for K-tile 0
    float v[32];
    {
        const float* xc = x + ((size_t)b * C_ + ch * 32) * HW + p0 + sp;
        #pragma unroll
        for (int i = 0; i < 32; ++i) v[i] = xc[(size_t)i * HW];
    }

    for (int it = 0; it < 8; ++it) {
        int k0 = it * 64;

        // --- W phase: cvt regs -> LDS (B), global_load_lds (A) ---
        #pragma unroll
        for (int g = 0; g < 4; ++g) {
            bf16x8 bv;
            #pragma unroll
            for (int i = 0; i < 8; ++i) bv[i] = (bf16)v[g * 8 + i];
            int colb = ch * 64 + g * 16;          // byte col within 128B row
            *(bf16x8*)(Bl + sp * 128 + (colb ^ sw)) = bv;
        }
        #pragma unroll
        for (int q = 0; q < 4; ++q) {
            int L   = (q * 256 + tid) * 16;       // linear dest byte
            int row = L >> 7;
            int kb  = (L & 127) ^ ((row & 7) << 4);
            gl_lds16(W2 + (size_t)(m0 + row) * C_ + k0 + (kb >> 1), Al + L);
        }
        __syncthreads();                          // tiles ready (vmcnt+lgkm drained)

        // --- R phase: prefetch iter+1 regs, then MFMA from LDS ---
        if (it < 7) {
            const float* xc = x + ((size_t)b * C_ + k0 + 64 + ch * 32) * HW + p0 + sp;
            #pragma unroll
            for (int i = 0; i < 32; ++i) v[i] = xc[(size_t)i * HW];
        }
        #pragma unroll
        for (int ks = 0; ks < 2; ++ks) {
            int kb0 = ks * 64 + ((lane >> 4) << 4);
            bf16x8 a[4], bb[4];
            #pragma unroll
            for (int j = 0; j < 4; ++j) {
                int row = wn * 64 + j * 16 + (lane & 15);
                bb[j] = *(const bf16x8*)(Bl + row * 128 + (kb0 ^ ((row & 7) << 4)));
            }
            #pragma unroll
            for (int i = 0; i < 4; ++i) {
                int row = wm * 64 + i * 16 + (lane & 15);
                a[i] = *(const bf16x8*)(Al + row * 128 + (kb0 ^ ((row & 7) << 4)));
            }
            #pragma unroll
            for (int i = 0; i < 4; ++i)
                #pragma unroll
                for (int j = 0; j < 4; ++j)
                    acc[i][j] = __builtin_amdgcn_mfma_f32_16x16x32_bf16(
                                    a[i], bb[j], acc[i][j], 0, 0, 0);
            if (wm == 0) {                        // score MFMA (wave-uniform gate)
                bf16x8 aq = *(const bf16x8*)(
                    Qkb + ((size_t)b * 16 + (lane & 15)) * C_
                        + k0 + ks * 32 + ((lane >> 4) << 3));
                #pragma unroll
                for (int j = 0; j < 4; ++j)
                    acc_q[j] = __builtin_amdgcn_mfma_f32_16x16x32_bf16(
                                   aq, bb[j], acc_q[j], 0, 0, 0);
            }
        }
        __syncthreads();                          // readers done; LDS reusable
    }

    // --- scores -> att (wid 0,1 hold them; rows n = 0..7 live in lanes 0..31)
    if (wid < 2 && lane < 32) {
        #pragma unroll
        for (int j = 0; j < 4; ++j)
            #pragma unroll
            for (int r = 0; r < 4; ++r) {
                int n = (lane >> 4) * 4 + r;
                att[n][wn * 64 + j * 16 + (lane & 15)] = acc_q[j][r];
            }
    }
    __syncthreads();

    // --- softmax over w (rows of 64) ---
    #pragma unroll
    for (int nn = 0; nn < 2; ++nn) {
        int n = wid * 2 + nn;
        #pragma unroll
        for (int rr = 0; rr < 2; ++rr) {
            int p = rr * 64 + lane;
            float t = att[n][p];                  // already scaled by 1/sqrt(768)
            float mx = t;
            #pragma unroll
            for (int off = 32; off; off >>= 1) mx = fmaxf(mx, __shfl_xor(mx, off));
            float e = __expf(t - mx);
            float sm = e;
            #pragma unroll
            for (int off = 32; off; off >>= 1) sm += __shfl_xor(sm, off);
            att[n][p] = e / sm;
        }
    }
    __syncthreads();
    if (tid < 128) {
        float sv = 0.f;
        #pragma unroll
        for (int n = 0; n < N_; ++n) sv += att[n][tid];
        s_lds[tid] = sv;
    }
    __syncthreads();

    // --- epilogue: out = x + wo_b + s*(acc + b2) ---
    int r4 = (lane >> 4) << 2;
    int cl = lane & 15;
    #pragma unroll
    for (int j = 0; j < 4; ++j) {
        int pl = wn * 64 + j * 16 + cl;
        float sv = s_lds[pl];
        #pragma unroll
        for (int i = 0; i < 4; ++i) {
            int ob = m0 + wm * 64 + i * 16 + r4;
            f32x4 b2v = *(const f32x4*)(b2 + ob);
            f32x4 wbv = *(const f32x4*)(wo_b + ob);
            #pragma unroll
            for (int r = 0; r < 4; ++r) {
                size_t gi = ((size_t)b * C_ + ob + r) * HW + p0 + pl;
                out[gi] = x[gi] + wbv[r] + sv * (acc[i][j][r] + b2v[r]);
            }
        }
    }
}

// ---------------------------------------------------------------------------
extern "C" void kernel_launch(void* const* d_in, const int* in_sizes, int n_in,
                              void* d_out, int out_size, void* d_ws, size_t ws_size,
                              hipStream_t stream) {
    const float* x    = (const float*)d_in[0];
    const float* se   = (const float*)d_in[1];
    const float* wts  = (const float*)d_in[2];
    const float* wq_w = (const float*)d_in[3];
    const float* wq_b = (const float*)d_in[4];
    const float* wk_w = (const float*)d_in[5];
    // d_in[6] = wk_b: constant over softmax axis -> cancels, unused
    const float* wv_w = (const float*)d_in[7];
    const float* wv_b = (const float*)d_in[8];
    const float* wo_w = (const float*)d_in[9];
    const float* wo_b = (const float*)d_in[10];
    float* out = (float*)d_out;

    // workspace layout (<1MB)
    char* ws = (char*)d_ws;
    bf16*  Qkb = (bf16*) (ws + 0);          // 256KB  [16][16][512], rows 8..15 zero
    bf16*  W2  = (bf16*) (ws + 262144);     // 512KB
    float* b2  = (float*)(ws + 786432);     // 2KB

    k_qq    <<<dim3(256),  dim3(512), 0, stream>>>(se, wts, wq_w, wq_b, wk_w, Qkb);
    k_w2    <<<dim3(128),  dim3(512), 0, stream>>>(wo_w, wv_w, wv_b, W2, b2);
    k_fused <<<dim3(2048), dim3(256), 0, stream>>>(x, W2, b2, wo_b, Qkb, out);
}

// Round 5
// 197.027 us; speedup vs baseline: 1.6236x; 1.1291x over previous
//
#include <hip/hip_runtime.h>
#include <hip/hip_bf16.h>

// Problem dims (fixed by reference setup)
#define B_   16
#define N_   8
#define C_   512
#define D_   768
#define HH   64
#define WW   64
#define HW   4096          // 64*64 pixels per batch

typedef __bf16 bf16;
typedef __attribute__((ext_vector_type(8))) __bf16 bf16x8;
typedef __attribute__((ext_vector_type(4))) __bf16 bf16x4;
typedef __attribute__((ext_vector_type(4))) float  f32x4;

// ---------------------------------------------------------------------------
// K1 (merged pre-pass).
// Blocks 0..255   : Qkb[b,n',m] = bf16( (Q[b,n',:]·wk_w[:,m]) / sqrt(768) ),
//                   Q computed in-LDS from se*weights; rows n'>=8 zero-padded.
// Blocks 256..511 : W2[o,c] = wo_w[o,:]·wv_w[:,c] (bf16), 2 o-rows per block;
//                   b2[o] = wo_w[o,:]·wv_b.
__global__ __launch_bounds__(512) void k_pre(const float* __restrict__ se,
                                             const float* __restrict__ weights,
                                             const float* __restrict__ wq_w,
                                             const float* __restrict__ wq_b,
                                             const float* __restrict__ wk_w,
                                             const float* __restrict__ wo_w,
                                             const float* __restrict__ wv_w,
                                             const float* __restrict__ wv_b,
                                             bf16* __restrict__ Qkb,
                                             bf16* __restrict__ W2,
                                             float* __restrict__ b2) {
    int tid = threadIdx.x;
    if (blockIdx.x < 256) {
        int blk = blockIdx.x;                 // b*16 + n'
        int b = blk >> 4, n = blk & 15;
        if (n >= 8) {                         // zero padding rows
            Qkb[(size_t)blk * C_ + tid] = (bf16)0.f;
            return;
        }
        __shared__ float we[D_];
        __shared__ float Q_lds[C_];
        const float* se_row = se + (size_t)(b * N_ + n) * D_;
        float wt = weights[n];
        for (int d = tid; d < D_; d += 512) we[d] = se_row[d] * wt;
        __syncthreads();

        int c = tid;
        const f32x4* wr = (const f32x4*)(wq_w + (size_t)c * D_);
        float acc = wq_b[c];
        #pragma unroll 4
        for (int i = 0; i < D_ / 4; ++i) {
            f32x4 w4 = wr[i];
            acc += we[4*i+0] * w4[0] + we[4*i+1] * w4[1]
                 + we[4*i+2] * w4[2] + we[4*i+3] * w4[3];
        }
        Q_lds[c] = acc;
        __syncthreads();

        int m = tid;
        float a2 = 0.f;
        #pragma unroll 8
        for (int o = 0; o < C_; ++o)
            a2 = fmaf(Q_lds[o], wk_w[(size_t)o * C_ + m], a2);
        Qkb[(size_t)blk * C_ + m] = (bf16)(a2 * 3.6084391824351615e-2f);
    } else {
        int o0 = (blockIdx.x - 256) * 2;
        int c  = tid;
        const float* r0 = wo_w + (size_t)o0 * C_;
        float a0 = 0.f, a1 = 0.f;
        #pragma unroll 8
        for (int m = 0; m < C_; ++m) {
            float v = wv_w[(size_t)m * C_ + c];
            a0 = fmaf(r0[m],      v, a0);
            a1 = fmaf(r0[C_ + m], v, a1);
        }
        W2[(size_t)(o0 + 0) * C_ + c] = (bf16)a0;
        W2[(size_t)(o0 + 1) * C_ + c] = (bf16)a1;
        if (c < 2) {
            float sb = 0.f;
            const float* rr = wo_w + (size_t)(o0 + c) * C_;
            #pragma unroll 4
            for (int m = 0; m < C_; ++m) sb = fmaf(rr[m], wv_b[m], sb);
            b2[o0 + c] = sb;
        }
    }
}

// ---------------------------------------------------------------------------
// K2 (fused, software-pipelined): per block (b, pt, mt):
//   GEMM acc[o,p] = W2[m-tile]·x[:,p-tile]   (MFMA; A via global_load_lds)
//   scores t[n,p] = Qkb[n,:]·x[:,p-tile]     (MFMA; shares B fragments)
//   softmax over w -> s[p];  out = x + wo_b + s*(acc + b2)
// Double-buffered LDS, raw s_barrier + counted vmcnt (T3/T4):
// at every barrier, exactly the 32 next-next x-loads stay in flight.

__device__ __forceinline__ void gl_lds16(const void* g, void* l) {
    __builtin_amdgcn_global_load_lds(
        (const __attribute__((address_space(1))) void*)g,
        (__attribute__((address_space(3))) void*)l, 16, 0, 0);
}

__global__ __launch_bounds__(256, 2) void k_fused(const float* __restrict__ x,
                                                  const bf16* __restrict__ W2,
                                                  const float* __restrict__ b2,
                                                  const float* __restrict__ wo_b,
                                                  const bf16* __restrict__ Qkb,
                                                  float* __restrict__ out) {
    // XCD-grouped mapping: the 4 m-tiles of one (b,pt) job land on one XCD,
    // dispatched adjacently -> x pixel-panel (256KB f32) L2 reuse.
    int id = blockIdx.x;
    int xcd = id & 7, chunk = id >> 3;
    int mt = chunk & 3, jrow = chunk >> 2;
    int job = jrow * 8 + xcd;                     // 0..511
    int b = job >> 5, pt = job & 31;
    int m0 = mt * 128;
    int p0 = pt * 128;                            // 2 complete h-rows

    __shared__ __align__(128) unsigned char Al[2][16384]; // [128 o][64 c] bf16, swz
    __shared__ __align__(128) unsigned char Bl[2][16384]; // [128 p][64 c] bf16, swz
    __shared__ float att[N_][128];
    __shared__ float s_lds[128];

    int tid = threadIdx.x;
    int wid = tid >> 6, lane = tid & 63;
    int wm = wid >> 1, wn = wid & 1;

    // staging roles: thread owns pixel sp (0..127) and c-half ch (32 c)
    int sp = lane + (wid & 1) * 64;
    int ch = wid >> 1;
    int sw = (sp & 7) << 4;

    f32x4 acc[4][4] = {};
    f32x4 acc_q[4] = {};

    const float* xbase = x + (size_t)b * C_ * HW + p0 + sp;

    // ---- prologue: stage tile 0, leave tile-1 x-loads in flight ----
    float v[32];
    {
        const float* xc = xbase + (size_t)(ch * 32) * HW;
        #pragma unroll
        for (int i = 0; i < 32; ++i) v[i] = xc[(size_t)i * HW];   // vm: 32
    }
    #pragma unroll
    for (int q = 0; q < 4; ++q) {
        int L   = (q * 256 + tid) * 16;
        int row = L >> 7;
        int kb  = (L & 127) ^ ((row & 7) << 4);
        gl_lds16(W2 + (size_t)(m0 + row) * C_ + (kb >> 1), &Al[0][L]); // vm: 36
    }
    #pragma unroll
    for (int g = 0; g < 4; ++g) {                 // compiler waits vmcnt(4) for v
        bf16x8 bv;
        #pragma unroll
        for (int i = 0; i < 8; ++i) bv[i] = (bf16)v[g * 8 + i];
        *(bf16x8*)(&Bl[0][sp * 128 + ((ch * 64 + g * 16) ^ sw)]) = bv;
    }
    {   // issue tile-1 x loads
        const float* xc = xbase + (size_t)(64 + ch * 32) * HW;
        #pragma unroll
        for (int i = 0; i < 32; ++i) v[i] = xc[(size_t)i * HW];   // vm: 4+32
    }
    asm volatile("s_waitcnt vmcnt(32)" ::: "memory");  // A0 landed in LDS
    asm volatile("s_waitcnt lgkmcnt(0)" ::: "memory"); // B0 writes visible
    __builtin_amdgcn_s_barrier();

    // ---- main loop: t = 0..6 computes tile t, stages tile t+1 ----
    int c = 0;
    #pragma unroll 1
    for (int t = 0; t < 7; ++t) {
        int k0 = t * 64;
        // fragments of tile t from buf c
        bf16x8 a[4], bb[4][2];
        #pragma unroll
        for (int ks = 0; ks < 2; ++ks) {
            int kb0 = ks * 64 + ((lane >> 4) << 4);
            #pragma unroll
            for (int j = 0; j < 4; ++j) {
                int row = wn * 64 + j * 16 + (lane & 15);
                bb[j][ks] = *(const bf16x8*)(&Bl[c][row * 128 + (kb0 ^ ((row & 7) << 4))]);
            }
        }
        // stage A_{t+1} into other buffer
        #pragma unroll
        for (int q = 0; q < 4; ++q) {
            int L   = (q * 256 + tid) * 16;
            int row = L >> 7;
            int kb  = (L & 127) ^ ((row & 7) << 4);
            gl_lds16(W2 + (size_t)(m0 + row) * C_ + k0 + 64 + (kb >> 1),
                     &Al[c ^ 1][L]);              // vm: 32(v)+4
        }
        // MFMA on tile t
        __builtin_amdgcn_s_setprio(1);
        #pragma unroll
        for (int ks = 0; ks < 2; ++ks) {
            int kb0 = ks * 64 + ((lane >> 4) << 4);
            #pragma unroll
            for (int i = 0; i < 4; ++i) {
                int row = wm * 64 + i * 16 + (lane & 15);
                a[i] = *(const bf16x8*)(&Al[c][row * 128 + (kb0 ^ ((row & 7) << 4))]);
            }
            #pragma unroll
            for (int i = 0; i < 4; ++i)
                #pragma unroll
                for (int j = 0; j < 4; ++j)
                    acc[i][j] = __builtin_amdgcn_mfma_f32_16x16x32_bf16(
                                    a[i], bb[j][ks], acc[i][j], 0, 0, 0);
            if (wm == 0) {                        // score MFMA (wave-uniform)
                bf16x8 aq = *(const bf16x8*)(
                    Qkb + ((size_t)b * 16 + (lane & 15)) * C_
                        + k0 + ks * 32 + ((lane >> 4) << 3));
                #pragma unroll
                for (int j = 0; j < 4; ++j)
                    acc_q[j] = __builtin_amdgcn_mfma_f32_16x16x32_bf16(
                                   aq, bb[j][ks], acc_q[j], 0, 0, 0);
            }
        }
        __builtin_amdgcn_s_setprio(0);
        // convert v (tile t+1) -> Bl[c^1]; compiler inserts vmcnt for v reads
        #pragma unroll
        for (int g = 0; g < 4; ++g) {
            bf16x8 bv;
            #pragma unroll
            for (int i = 0; i < 8; ++i) bv[i] = (bf16)v[g * 8 + i];
            *(bf16x8*)(&Bl[c ^ 1][sp * 128 + ((ch * 64 + g * 16) ^ sw)]) = bv;
        }
        if (t < 6) {                              // issue tile t+2 x loads
            const float* xc = xbase + (size_t)(k0 + 128 + ch * 32) * HW;
            #pragma unroll
            for (int i = 0; i < 32; ++i) v[i] = xc[(size_t)i * HW]; // vm: 4+32
            asm volatile("s_waitcnt vmcnt(32)" ::: "memory");  // A_{t+1} landed
        } else {
            asm volatile("s_waitcnt vmcnt(0)" ::: "memory");   // drain all
        }
        asm volatile("s_waitcnt lgkmcnt(0)" ::: "memory");     // B writes visible
        __builtin_amdgcn_s_barrier();
        c ^= 1;
    }

    // ---- peeled tile 7: compute only ----
    {
        #pragma unroll
        for (int ks = 0; ks < 2; ++ks) {
            int kb0 = ks * 64 + ((lane >> 4) << 4);
            bf16x8 a[4], bb[4];
            #pragma unroll
            for (int j = 0; j < 4; ++j) {
                int row = wn * 64 + j * 16 + (lane & 15);
                bb[j] = *(const bf16x8*)(&Bl[c][row * 128 + (kb0 ^ ((row & 7) << 4))]);
            }
            #pragma unroll
            for (int i = 0; i < 4; ++i) {
                int row = wm * 64 + i * 16 + (lane & 15);
                a[i] = *(const bf16x8*)(&Al[c][row * 128 + (kb0 ^ ((row & 7) << 4))]);
            }
            #pragma unroll
            for (int i = 0; i < 4; ++i)
                #pragma unroll
                for (int j = 0; j < 4; ++j)
                    acc[i][j] = __builtin_amdgcn_mfma_f32_16x16x32_bf16(
                                    a[i], bb[j], acc[i][j], 0, 0, 0);
            if (wm == 0) {
                bf16x8 aq = *(const bf16x8*)(
                    Qkb + ((size_t)b * 16 + (lane & 15)) * C_
                        + 448 + ks * 32 + ((lane >> 4) << 3));
                #pragma unroll
                for (int j = 0; j < 4; ++j)
                    acc_q[j] = __builtin_amdgcn_mfma_f32_16x16x32_bf16(
                                   aq, bb[j], acc_q[j], 0, 0, 0);
            }
        }
    }

    // --- scores -> att (wid 0,1 hold them; n rows live per 16-lane groups) ---
    if (wid < 2 && lane < 32) {
        #pragma unroll
        for (int j = 0; j < 4; ++j)
            #pragma unroll
            for (int r = 0; r < 4; ++r) {
                int n = (lane >> 4) * 4 + r;
                att[n][wn * 64 + j * 16 + (lane & 15)] = acc_q[j][r];
            }
    }
    __syncthreads();

    // --- softmax over w (rows of 64) ---
    #pragma unroll
    for (int nn = 0; nn < 2; ++nn) {
        int n = wid * 2 + nn;
        #pragma unroll
        for (int rr = 0; rr < 2; ++rr) {
            int p = rr * 64 + lane;
            float tt = att[n][p];                 // already scaled by 1/sqrt(768)
            float mx = tt;
            #pragma unroll
            for (int off = 32; off; off >>= 1) mx = fmaxf(mx, __shfl_xor(mx, off));
            float e = __expf(tt - mx);
            float sm = e;
            #pragma unroll
            for (int off = 32; off; off >>= 1) sm += __shfl_xor(sm, off);
            att[n][p] = e / sm;
        }
    }
    __syncthreads();
    if (tid < 128) {
        float sv = 0.f;
        #pragma unroll
        for (int n = 0; n < N_; ++n) sv += att[n][tid];
        s_lds[tid] = sv;
    }
    __syncthreads();

    // --- epilogue: out = x + wo_b + s*(acc + b2) ---
    int r4 = (lane >> 4) << 2;
    int cl = lane & 15;
    #pragma unroll
    for (int j = 0; j < 4; ++j) {
        int pl = wn * 64 + j * 16 + cl;
        float sv = s_lds[pl];
        #pragma unroll
        for (int i = 0; i < 4; ++i) {
            int ob = m0 + wm * 64 + i * 16 + r4;
            f32x4 b2v = *(const f32x4*)(b2 + ob);
            f32x4 wbv = *(const f32x4*)(wo_b + ob);
            #pragma unroll
            for (int r = 0; r < 4; ++r) {
                size_t gi = ((size_t)b * C_ + ob + r) * HW + p0 + pl;
                out[gi] = x[gi] + wbv[r] + sv * (acc[i][j][r] + b2v[r]);
            }
        }
    }
}

// ---------------------------------------------------------------------------
extern "C" void kernel_launch(void* const* d_in, const int* in_sizes, int n_in,
                              void* d_out, int out_size, void* d_ws, size_t ws_size,
                              hipStream_t stream) {
    const float* x    = (const float*)d_in[0];
    const float* se   = (const float*)d_in[1];
    const float* wts  = (const float*)d_in[2];
    const float* wq_w = (const float*)d_in[3];
    const float* wq_b = (const float*)d_in[4];
    const float* wk_w = (const float*)d_in[5];
    // d_in[6] = wk_b: constant over softmax axis -> cancels, unused
    const float* wv_w = (const float*)d_in[7];
    const float* wv_b = (const float*)d_in[8];
    const float* wo_w = (const float*)d_in[9];
    const float* wo_b = (const float*)d_in[10];
    float* out = (float*)d_out;

    // workspace layout (<1MB)
    char* ws = (char*)d_ws;
    bf16*  Qkb = (bf16*) (ws + 0);          // 256KB  [16][16][512], rows 8..15 zero
    bf16*  W2  = (bf16*) (ws + 262144);     // 512KB
    float* b2  = (float*)(ws + 786432);     // 2KB

    k_pre   <<<dim3(512),  dim3(512), 0, stream>>>(se, wts, wq_w, wq_b, wk_w,
                                                   wo_w, wv_w, wv_b, Qkb, W2, b2);
    k_fused <<<dim3(2048), dim3(256), 0, stream>>>(x, W2, b2, wo_b, Qkb, out);
}

// Round 6
// 189.997 us; speedup vs baseline: 1.6837x; 1.0370x over previous
//
#include <hip/hip_runtime.h>
#include <hip/hip_bf16.h>

// Problem dims (fixed by reference setup)
#define B_   16
#define N_   8
#define C_   512
#define D_   768
#define HH   64
#define WW   64
#define HW   4096          // 64*64 pixels per batch

typedef __bf16 bf16;
typedef __attribute__((ext_vector_type(8))) __bf16 bf16x8;
typedef __attribute__((ext_vector_type(4))) __bf16 bf16x4;
typedef __attribute__((ext_vector_type(4))) float  f32x4;

// ---------------------------------------------------------------------------
// K1 (merged pre-pass).
// Blocks 0..255   : Qkb[b,n',m] = bf16( (Q[b,n',:]·wk_w[:,m]) / sqrt(768) ),
//                   Q computed in-LDS from se*weights; rows n'>=8 zero-padded.
// Blocks 256..511 : W2[o,c] = wo_w[o,:]·wv_w[:,c] (bf16), 2 o-rows per block;
//                   b2[o] = wo_w[o,:]·wv_b.
__global__ __launch_bounds__(512) void k_pre(const float* __restrict__ se,
                                             const float* __restrict__ weights,
                                             const float* __restrict__ wq_w,
                                             const float* __restrict__ wq_b,
                                             const float* __restrict__ wk_w,
                                             const float* __restrict__ wo_w,
                                             const float* __restrict__ wv_w,
                                             const float* __restrict__ wv_b,
                                             bf16* __restrict__ Qkb,
                                             bf16* __restrict__ W2,
                                             float* __restrict__ b2) {
    int tid = threadIdx.x;
    if (blockIdx.x < 256) {
        int blk = blockIdx.x;                 // b*16 + n'
        int b = blk >> 4, n = blk & 15;
        if (n >= 8) {                         // zero padding rows
            Qkb[(size_t)blk * C_ + tid] = (bf16)0.f;
            return;
        }
        __shared__ float we[D_];
        __shared__ float Q_lds[C_];
        const float* se_row = se + (size_t)(b * N_ + n) * D_;
        float wt = weights[n];
        for (int d = tid; d < D_; d += 512) we[d] = se_row[d] * wt;
        __syncthreads();

        int c = tid;
        const f32x4* wr = (const f32x4*)(wq_w + (size_t)c * D_);
        float acc = wq_b[c];
        #pragma unroll 4
        for (int i = 0; i < D_ / 4; ++i) {
            f32x4 w4 = wr[i];
            acc += we[4*i+0] * w4[0] + we[4*i+1] * w4[1]
                 + we[4*i+2] * w4[2] + we[4*i+3] * w4[3];
        }
        Q_lds[c] = acc;
        __syncthreads();

        int m = tid;
        float a2 = 0.f;
        #pragma unroll 8
        for (int o = 0; o < C_; ++o)
            a2 = fmaf(Q_lds[o], wk_w[(size_t)o * C_ + m], a2);
        Qkb[(size_t)blk * C_ + m] = (bf16)(a2 * 3.6084391824351615e-2f);
    } else {
        int o0 = (blockIdx.x - 256) * 2;
        int c  = tid;
        const float* r0 = wo_w + (size_t)o0 * C_;
        float a0 = 0.f, a1 = 0.f;
        #pragma unroll 8
        for (int m = 0; m < C_; ++m) {
            float v = wv_w[(size_t)m * C_ + c];
            a0 = fmaf(r0[m],      v, a0);
            a1 = fmaf(r0[C_ + m], v, a1);
        }
        W2[(size_t)(o0 + 0) * C_ + c] = (bf16)a0;
        W2[(size_t)(o0 + 1) * C_ + c] = (bf16)a1;
        if (c < 2) {
            float sb = 0.f;
            const float* rr = wo_w + (size_t)(o0 + c) * C_;
            #pragma unroll 4
            for (int m = 0; m < C_; ++m) sb = fmaf(rr[m], wv_b[m], sb);
            b2[o0 + c] = sb;
        }
    }
}

// ---------------------------------------------------------------------------
// K2 (fused v3, full-M column): per block (b, pt):
//   acc[o,p] = W2[ALL 512 o]·x[:,p-tile]   -- x (B-operand) read ONCE
//   scores t[n,p] = Qkb[n,:]·x[:,p-tile]   (MFMA; shares B fragments)
//   softmax over w -> s[p];  out = x + wo_b + s*(acc + b2)
// 512 thr / 8 waves; wave (wm=wid>>1, wp=wid&1) owns 128o x 64p; acc[8][4].
// A (W2) single-buffered 64KB via global_load_lds; B double-buffered 2x16KB,
// reg-staged f32->bf16 one tile ahead.  m97-style 2 barriers per K-step.

__device__ __forceinline__ void gl_lds16(const void* g, void* l) {
    __builtin_amdgcn_global_load_lds(
        (const __attribute__((address_space(1))) void*)g,
        (__attribute__((address_space(3))) void*)l, 16, 0, 0);
}

__global__ __launch_bounds__(512, 2) void k_fused(const float* __restrict__ x,
                                                  const bf16* __restrict__ W2,
                                                  const float* __restrict__ b2,
                                                  const float* __restrict__ wo_b,
                                                  const bf16* __restrict__ Qkb,
                                                  float* __restrict__ out) {
    // XCD swizzle (512 % 8 == 0 -> bijective)
    int id = blockIdx.x;
    int job = (id & 7) * 64 + (id >> 3);          // 0..511
    int b = job >> 5, pt = job & 31;
    int p0 = pt * 128;                            // 2 complete h-rows

    __shared__ __align__(128) unsigned char Al[65536];    // [512 o][64 c] bf16, swz
    __shared__ __align__(128) unsigned char Bl[2][16384]; // [128 p][64 c] bf16, swz
    __shared__ float att[N_][128];
    __shared__ float s_lds[128];

    int tid = threadIdx.x;
    int wid = tid >> 6, lane = tid & 63;
    int wm = wid >> 1, wp = wid & 1;

    // B staging role: thread owns 4 consecutive pixels (pq) x 4 c's (cs)
    int pq = tid & 31;                            // pixels pq*4 .. pq*4+3
    int cs = tid >> 5;                            // c = k0 + cs*4 + i

    f32x4 acc[8][4] = {};
    f32x4 acc_q[4] = {};

    const float* xb = x + (size_t)b * C_ * HW + p0 + pq * 4;

    // ---- prologue ----
    f32x4 vv[4];
    #pragma unroll
    for (int i = 0; i < 4; ++i)                   // B0 loads (4 vm)
        vv[i] = *(const f32x4*)(xb + (size_t)(cs * 4 + i) * HW);
    #pragma unroll
    for (int q = 0; q < 8; ++q) {                 // A0 gloads (8 vm)
        int L   = (q * 512 + tid) * 16;
        int row = L >> 7;
        int kb  = (L & 127) ^ ((row & 7) << 4);
        gl_lds16(W2 + (size_t)row * C_ + (kb >> 1), &Al[L]);
    }
    #pragma unroll
    for (int j = 0; j < 4; ++j) {                 // cvt B0 -> Bl[0] (waits B0)
        int p = pq * 4 + j;
        bf16x4 bv; bv[0]=(bf16)vv[0][j]; bv[1]=(bf16)vv[1][j];
                   bv[2]=(bf16)vv[2][j]; bv[3]=(bf16)vv[3][j];
        *(bf16x4*)(&Bl[0][p * 128 + ((cs * 8) ^ ((p & 7) << 4))]) = bv;
    }
    #pragma unroll
    for (int i = 0; i < 4; ++i)                   // B1 loads (4 vm)
        vv[i] = *(const f32x4*)(xb + (size_t)(64 + cs * 4 + i) * HW);
    asm volatile("s_waitcnt vmcnt(4)" ::: "memory");   // A0 landed in LDS
    asm volatile("s_waitcnt lgkmcnt(0)" ::: "memory"); // B0 writes visible
    __builtin_amdgcn_s_barrier();

    // ---- main loop: t computes tile t from Al/Bl[c], stages t+1 ----
    int c = 0;
    #pragma unroll 1
    for (int t = 0; t < 7; ++t) {
        int k0 = t * 64;
        // MFMA phase
        __builtin_amdgcn_s_setprio(1);
        #pragma unroll
        for (int ks = 0; ks < 2; ++ks) {
            int kb0 = ks * 64 + ((lane >> 4) << 4);
            bf16x8 bb[4];
            #pragma unroll
            for (int j = 0; j < 4; ++j) {
                int row = wp * 64 + j * 16 + (lane & 15);
                bb[j] = *(const bf16x8*)(&Bl[c][row * 128 + (kb0 ^ ((row & 7) << 4))]);
            }
            #pragma unroll
            for (int i = 0; i < 8; ++i) {
                int row = wm * 128 + i * 16 + (lane & 15);
                bf16x8 a = *(const bf16x8*)(&Al[row * 128 + (kb0 ^ ((row & 7) << 4))]);
                #pragma unroll
                for (int j = 0; j < 4; ++j)
                    acc[i][j] = __builtin_amdgcn_mfma_f32_16x16x32_bf16(
                                    a, bb[j], acc[i][j], 0, 0, 0);
            }
            if (wm == 0) {                        // score MFMA (wave-uniform)
                bf16x8 aq = *(const bf16x8*)(
                    Qkb + ((size_t)b * 16 + (lane & 15)) * C_
                        + k0 + ks * 32 + ((lane >> 4) << 3));
                #pragma unroll
                for (int j = 0; j < 4; ++j)
                    acc_q[j] = __builtin_amdgcn_mfma_f32_16x16x32_bf16(
                                   aq, bb[j], acc_q[j], 0, 0, 0);
            }
        }
        __builtin_amdgcn_s_setprio(0);
        __builtin_amdgcn_s_barrier();             // all Al/Bl[c] reads done

        // stage A_{t+1} (8 vm)
        #pragma unroll
        for (int q = 0; q < 8; ++q) {
            int L   = (q * 512 + tid) * 16;
            int row = L >> 7;
            int kb  = (L & 127) ^ ((row & 7) << 4);
            gl_lds16(W2 + (size_t)row * C_ + k0 + 64 + (kb >> 1), &Al[L]);
        }
        // cvt B_{t+1} -> Bl[c^1] (compiler waits the 4 v-loads; 1-iter cover)
        #pragma unroll
        for (int j = 0; j < 4; ++j) {
            int p = pq * 4 + j;
            bf16x4 bv; bv[0]=(bf16)vv[0][j]; bv[1]=(bf16)vv[1][j];
                       bv[2]=(bf16)vv[2][j]; bv[3]=(bf16)vv[3][j];
            *(bf16x4*)(&Bl[c ^ 1][p * 128 + ((cs * 8) ^ ((p & 7) << 4))]) = bv;
        }
        if (t < 6) {                              // issue B_{t+2} (4 vm)
            #pragma unroll
            for (int i = 0; i < 4; ++i)
                vv[i] = *(const f32x4*)(xb + (size_t)(k0 + 128 + cs * 4 + i) * HW);
            asm volatile("s_waitcnt vmcnt(4)" ::: "memory");  // A_{t+1} landed
        } else {
            asm volatile("s_waitcnt vmcnt(0)" ::: "memory");
        }
        asm volatile("s_waitcnt lgkmcnt(0)" ::: "memory");    // B writes visible
        __builtin_amdgcn_s_barrier();
        c ^= 1;
    }

    // ---- peeled tile 7: compute only ----
    #pragma unroll
    for (int ks = 0; ks < 2; ++ks) {
        int kb0 = ks * 64 + ((lane >> 4) << 4);
        bf16x8 bb[4];
        #pragma unroll
        for (int j = 0; j < 4; ++j) {
            int row = wp * 64 + j * 16 + (lane & 15);
            bb[j] = *(const bf16x8*)(&Bl[c][row * 128 + (kb0 ^ ((row & 7) << 4))]);
        }
        #pragma unroll
        for (int i = 0; i < 8; ++i) {
            int row = wm * 128 + i * 16 + (lane & 15);
            bf16x8 a = *(const bf16x8*)(&Al[row * 128 + (kb0 ^ ((row & 7) << 4))]);
            #pragma unroll
            for (int j = 0; j < 4; ++j)
                acc[i][j] = __builtin_amdgcn_mfma_f32_16x16x32_bf16(
                                a, bb[j], acc[i][j], 0, 0, 0);
        }
        if (wm == 0) {
            bf16x8 aq = *(const bf16x8*)(
                Qkb + ((size_t)b * 16 + (lane & 15)) * C_
                    + 448 + ks * 32 + ((lane >> 4) << 3));
            #pragma unroll
            for (int j = 0; j < 4; ++j)
                acc_q[j] = __builtin_amdgcn_mfma_f32_16x16x32_bf16(
                               aq, bb[j], acc_q[j], 0, 0, 0);
        }
    }

    // --- scores -> att (wid 0,1 hold them; n rows per 16-lane groups) ---
    if (wid < 2 && lane < 32) {
        #pragma unroll
        for (int j = 0; j < 4; ++j)
            #pragma unroll
            for (int r = 0; r < 4; ++r) {
                int n = (lane >> 4) * 4 + r;
                att[n][wp * 64 + j * 16 + (lane & 15)] = acc_q[j][r];
            }
    }
    __syncthreads();

    // --- softmax over w (rows of 64): wave wid handles n=wid ---
    {
        int n = wid;
        #pragma unroll
        for (int rr = 0; rr < 2; ++rr) {
            int p = rr * 64 + lane;
            float tt = att[n][p];                 // already scaled by 1/sqrt(768)
            float mx = tt;
            #pragma unroll
            for (int off = 32; off; off >>= 1) mx = fmaxf(mx, __shfl_xor(mx, off));
            float e = __expf(tt - mx);
            float sm = e;
            #pragma unroll
            for (int off = 32; off; off >>= 1) sm += __shfl_xor(sm, off);
            att[n][p] = e / sm;
        }
    }
    __syncthreads();
    if (tid < 128) {
        float sv = 0.f;
        #pragma unroll
        for (int n = 0; n < N_; ++n) sv += att[n][tid];
        s_lds[tid] = sv;
    }
    __syncthreads();

    // --- epilogue: out = x + wo_b + s*(acc + b2) ---
    int r4 = (lane >> 4) << 2;
    int cl = lane & 15;
    #pragma unroll
    for (int j = 0; j < 4; ++j) {
        int pl = wp * 64 + j * 16 + cl;
        float sv = s_lds[pl];
        #pragma unroll
        for (int i = 0; i < 8; ++i) {
            int ob = wm * 128 + i * 16 + r4;
            f32x4 b2v = *(const f32x4*)(b2 + ob);
            f32x4 wbv = *(const f32x4*)(wo_b + ob);
            #pragma unroll
            for (int r = 0; r < 4; ++r) {
                size_t gi = ((size_t)b * C_ + ob + r) * HW + p0 + pl;
                out[gi] = x[gi] + wbv[r] + sv * (acc[i][j][r] + b2v[r]);
            }
        }
    }
}

// ---------------------------------------------------------------------------
extern "C" void kernel_launch(void* const* d_in, const int* in_sizes, int n_in,
                              void* d_out, int out_size, void* d_ws, size_t ws_size,
                              hipStream_t stream) {
    const float* x    = (const float*)d_in[0];
    const float* se   = (const float*)d_in[1];
    const float* wts  = (const float*)d_in[2];
    const float* wq_w = (const float*)d_in[3];
    const float* wq_b = (const float*)d_in[4];
    const float* wk_w = (const float*)d_in[5];
    // d_in[6] = wk_b: constant over softmax axis -> cancels, unused
    const float* wv_w = (const float*)d_in[7];
    const float* wv_b = (const float*)d_in[8];
    const float* wo_w = (const float*)d_in[9];
    const float* wo_b = (const float*)d_in[10];
    float* out = (float*)d_out;

    // workspace layout (<1MB)
    char* ws = (char*)d_ws;
    bf16*  Qkb = (bf16*) (ws + 0);          // 256KB  [16][16][512], rows 8..15 zero
    bf16*  W2  = (bf16*) (ws + 262144);     // 512KB
    float* b2  = (float*)(ws + 786432);     // 2KB

    k_pre   <<<dim3(512), dim3(512), 0, stream>>>(se, wts, wq_w, wq_b, wk_w,
                                                  wo_w, wv_w, wv_b, Qkb, W2, b2);
    k_fused <<<dim3(512), dim3(512), 0, stream>>>(x, W2, b2, wo_b, Qkb, out);
}

// Round 7
// 158.390 us; speedup vs baseline: 2.0197x; 1.1996x over previous
//
#include <hip/hip_runtime.h>
#include <hip/hip_bf16.h>

// Problem dims (fixed by reference setup)
#define B_   16
#define N_   8
#define C_   512
#define D_   768
#define HH   64
#define WW   64
#define HW   4096          // 64*64 pixels per batch

typedef __bf16 bf16;
typedef __attribute__((ext_vector_type(8))) __bf16 bf16x8;
typedef __attribute__((ext_vector_type(4))) __bf16 bf16x4;
typedef __attribute__((ext_vector_type(4))) float  f32x4;

// ---------------------------------------------------------------------------
// K1 (merged pre-pass).
// Blocks 0..255   : Qkb[b,n',m] = bf16( (Q[b,n',:]·wk_w[:,m]) / sqrt(768) ),
//                   Q computed in-LDS from se*weights; rows n'>=8 zero-padded.
// Blocks 256..511 : W2[o,c] = wo_w[o,:]·wv_w[:,c] (bf16), 2 o-rows per block;
//                   b2[o] = wo_w[o,:]·wv_b.
__global__ __launch_bounds__(512) void k_pre(const float* __restrict__ se,
                                             const float* __restrict__ weights,
                                             const float* __restrict__ wq_w,
                                             const float* __restrict__ wq_b,
                                             const float* __restrict__ wk_w,
                                             const float* __restrict__ wo_w,
                                             const float* __restrict__ wv_w,
                                             const float* __restrict__ wv_b,
                                             bf16* __restrict__ Qkb,
                                             bf16* __restrict__ W2,
                                             float* __restrict__ b2) {
    int tid = threadIdx.x;
    if (blockIdx.x < 256) {
        int blk = blockIdx.x;                 // b*16 + n'
        int b = blk >> 4, n = blk & 15;
        if (n >= 8) {                         // zero padding rows
            Qkb[(size_t)blk * C_ + tid] = (bf16)0.f;
            return;
        }
        __shared__ float we[D_];
        __shared__ float Q_lds[C_];
        const float* se_row = se + (size_t)(b * N_ + n) * D_;
        float wt = weights[n];
        for (int d = tid; d < D_; d += 512) we[d] = se_row[d] * wt;
        __syncthreads();

        int c = tid;
        const f32x4* wr = (const f32x4*)(wq_w + (size_t)c * D_);
        float acc = wq_b[c];
        #pragma unroll 4
        for (int i = 0; i < D_ / 4; ++i) {
            f32x4 w4 = wr[i];
            acc += we[4*i+0] * w4[0] + we[4*i+1] * w4[1]
                 + we[4*i+2] * w4[2] + we[4*i+3] * w4[3];
        }
        Q_lds[c] = acc;
        __syncthreads();

        int m = tid;
        float a2 = 0.f;
        #pragma unroll 8
        for (int o = 0; o < C_; ++o)
            a2 = fmaf(Q_lds[o], wk_w[(size_t)o * C_ + m], a2);
        Qkb[(size_t)blk * C_ + m] = (bf16)(a2 * 3.6084391824351615e-2f);
    } else {
        int o0 = (blockIdx.x - 256) * 2;
        int c  = tid;
        const float* r0 = wo_w + (size_t)o0 * C_;
        float a0 = 0.f, a1 = 0.f;
        #pragma unroll 8
        for (int m = 0; m < C_; ++m) {
            float v = wv_w[(size_t)m * C_ + c];
            a0 = fmaf(r0[m],      v, a0);
            a1 = fmaf(r0[C_ + m], v, a1);
        }
        W2[(size_t)(o0 + 0) * C_ + c] = (bf16)a0;
        W2[(size_t)(o0 + 1) * C_ + c] = (bf16)a1;
        if (c < 2) {
            float sb = 0.f;
            const float* rr = wo_w + (size_t)(o0 + c) * C_;
            #pragma unroll 4
            for (int m = 0; m < C_; ++m) sb = fmaf(rr[m], wv_b[m], sb);
            b2[o0 + c] = sb;
        }
    }
}

// ---------------------------------------------------------------------------
// K2 (fused v4): per block (b, pt): full-M GEMM over 128-pixel panel with
// PERSISTENT bf16 B-panel in LDS (doubles as the residual source):
//   Bp[128 p][512 c] bf16 (128KB, XOR-swizzled) -- written once per K-slice
//   Al[512 o][32 c]  bf16 (32KB, single-buffered, BK=32)
//   acc[o,p] += W2·x ; scores via MFMA on shared B frags; in-register softmax;
//   out = bf16(x) + wo_b + s*(acc + b2)   (residual read back from Bp)
// T14 reg-staging: A issued 1 tile ahead (L2 cover = MFMA phase), B issued
// 2 tiles ahead (HBM cover = 2 phases), static even/odd register sets.

__global__ __launch_bounds__(512, 2) void k_fused(const float* __restrict__ x,
                                                  const bf16* __restrict__ W2,
                                                  const float* __restrict__ b2,
                                                  const float* __restrict__ wo_b,
                                                  const bf16* __restrict__ Qkb,
                                                  float* __restrict__ out) {
    // XCD swizzle (512 % 8 == 0 -> bijective)
    int id = blockIdx.x;
    int job = (id & 7) * 64 + (id >> 3);          // 0..511
    int b = job >> 5, pt = job & 31;
    int p0 = pt * 128;                            // 2 complete h-rows

    __shared__ __align__(128) unsigned char Bp[131072]; // [128 p][512 c] bf16 swz
    __shared__ __align__(128) unsigned char Al[32768];  // [512 o][32 c] bf16 swz

    int tid = threadIdx.x;
    int wid = tid >> 6, lane = tid & 63;
    int wm = wid >> 1, wp = wid & 1;

    // B-stage role: thread owns ONE pixel, 8 channels per tile
    int pg = tid & 127, cg = tid >> 7;            // pixel, c-octet
    int fB = (pg & 63) << 4;                      // full-slot swizzle
    // A-stage role: thread owns 4 rows (one per 128-row group), 16B slot
    int r0 = tid >> 2, sl = tid & 3;
    int fA = ((r0 >> 1) & 3) << 4;

    f32x4 acc[8][4] = {};
    f32x4 acc_q[4] = {};

    const float* xb = x + (size_t)b * C_ * HW + p0 + pg;

    bf16x8 ar[4];
    float bvA[8], bvB[8];

#define ISSUE_A(K0)                                                           \
    { _Pragma("unroll")                                                       \
      for (int q = 0; q < 4; ++q)                                            \
          ar[q] = *(const bf16x8*)(W2 + (size_t)(q*128 + r0) * C_ + (K0) + sl*8); }

#define ISSUE_B(K0, BV)                                                       \
    { _Pragma("unroll")                                                       \
      for (int i = 0; i < 8; ++i)                                            \
          BV[i] = xb[(size_t)((K0) + cg*8 + i) * HW]; }

#define STAGE_WRITE(K0, BV)                                                   \
    { _Pragma("unroll")                                                       \
      for (int q = 0; q < 4; ++q)                                            \
          *(bf16x8*)(&Al[(q*128 + r0)*64 + ((sl*16) ^ fA)]) = ar[q];          \
      bf16x8 bw;                                                              \
      _Pragma("unroll")                                                       \
      for (int i = 0; i < 8; ++i) bw[i] = (bf16)BV[i];                        \
      *(bf16x8*)(&Bp[pg*1024 + ((((K0)*2) + cg*16) ^ fB)]) = bw; }

#define MFMA_TILE(K0)                                                         \
    { int kb = (K0)*2 + ((lane>>4)<<4);                                       \
      bf16x8 bbf[4];                                                          \
      _Pragma("unroll")                                                       \
      for (int j = 0; j < 4; ++j) {                                          \
          int row = wp*64 + j*16 + (lane&15);                                 \
          bbf[j] = *(const bf16x8*)(&Bp[row*1024 + (kb ^ ((row&63)<<4))]);    \
      }                                                                       \
      __builtin_amdgcn_s_setprio(1);                                          \
      _Pragma("unroll")                                                       \
      for (int i = 0; i < 8; ++i) {                                          \
          int row = wm*128 + i*16 + (lane&15);                                \
          bf16x8 av = *(const bf16x8*)(&Al[row*64 +                           \
                          (((lane>>4)<<4) ^ (((row>>1)&3)<<4))]);             \
          _Pragma("unroll")                                                   \
          for (int j = 0; j < 4; ++j)                                        \
              acc[i][j] = __builtin_amdgcn_mfma_f32_16x16x32_bf16(            \
                              av, bbf[j], acc[i][j], 0, 0, 0);                \
      }                                                                       \
      if (wm == 0) {                                                          \
          bf16x8 aq = *(const bf16x8*)(Qkb + ((size_t)b*16 + (lane&15))*C_    \
                                        + (K0) + ((lane>>4)<<3));             \
          _Pragma("unroll")                                                   \
          for (int j = 0; j < 4; ++j)                                        \
              acc_q[j] = __builtin_amdgcn_mfma_f32_16x16x32_bf16(             \
                             aq, bbf[j], acc_q[j], 0, 0, 0);                  \
      }                                                                       \
      __builtin_amdgcn_s_setprio(0); }

    // ---- prologue: A(0), B(0), B(1) in flight ----
    ISSUE_A(0);
    ISSUE_B(0,  bvA);
    ISSUE_B(32, bvB);

    #pragma unroll 1
    for (int tt = 0; tt < 8; ++tt) {
        int k0 = tt * 64;
        // ---- even tile (k0), consumes bvA ----
        STAGE_WRITE(k0, bvA);                     // compiler waits vmcnt for ar/bvA
        asm volatile("s_waitcnt lgkmcnt(0)" ::: "memory");
        __builtin_amdgcn_s_barrier();
        ISSUE_A(k0 + 32);                         // 1 tile ahead (L2)
        if (tt < 7) ISSUE_B(k0 + 64, bvA);        // 2 tiles ahead (HBM)
        MFMA_TILE(k0);
        __builtin_amdgcn_s_barrier();             // Al/Bp reads done
        // ---- odd tile (k0+32), consumes bvB ----
        STAGE_WRITE(k0 + 32, bvB);
        asm volatile("s_waitcnt lgkmcnt(0)" ::: "memory");
        __builtin_amdgcn_s_barrier();
        if (tt < 7) { ISSUE_A(k0 + 64); ISSUE_B(k0 + 96, bvB); }
        MFMA_TILE(k0 + 32);
        __builtin_amdgcn_s_barrier();
    }

    // ---- in-register softmax over w (64 px) on waves 0,1 ----
    // score[n][p]: n = (lane>>4)*4 + r (valid n<8 -> lanes 0..31),
    //              p = wp*64 + j*16 + (lane&15)
    float* s_lds = (float*)Al;                    // Al is dead now
    if (wm == 0) {
        float sm[4];
        #pragma unroll
        for (int r = 0; r < 4; ++r) {
            float m = fmaxf(fmaxf(acc_q[0][r], acc_q[1][r]),
                            fmaxf(acc_q[2][r], acc_q[3][r]));
            #pragma unroll
            for (int off = 1; off <= 8; off <<= 1) m = fmaxf(m, __shfl_xor(m, off));
            float s = 0.f;
            #pragma unroll
            for (int j = 0; j < 4; ++j) { acc_q[j][r] = __expf(acc_q[j][r] - m); s += acc_q[j][r]; }
            #pragma unroll
            for (int off = 1; off <= 8; off <<= 1) s += __shfl_xor(s, off);
            sm[r] = s;
        }
        f32x4 rcp;
        #pragma unroll
        for (int r = 0; r < 4; ++r) rcp[r] = 1.f / sm[r];
        #pragma unroll
        for (int j = 0; j < 4; ++j) {
            float sp = acc_q[j][0]*rcp[0] + acc_q[j][1]*rcp[1]
                     + acc_q[j][2]*rcp[2] + acc_q[j][3]*rcp[3];
            sp += __shfl_xor(sp, 16);             // add the other n-quad
            if (lane < 16) s_lds[wp*64 + j*16 + lane] = sp;
        }
    }
    __syncthreads();

    // ---- epilogue: out = bf16(x) + wo_b + s*(acc + b2); residual from Bp ----
    int r4 = (lane >> 4) << 2;
    int cl = lane & 15;
    #pragma unroll
    for (int j = 0; j < 4; ++j) {
        int pl = wp * 64 + j * 16 + cl;
        float sv = s_lds[pl];
        int fBp = (pl & 63) << 4;
        #pragma unroll
        for (int i = 0; i < 8; ++i) {
            int ob = wm * 128 + i * 16 + r4;
            f32x4 b2v = *(const f32x4*)(b2 + ob);
            f32x4 wbv = *(const f32x4*)(wo_b + ob);
            bf16x4 rx = *(const bf16x4*)(&Bp[pl*1024 + ((ob*2) ^ fBp)]);
            #pragma unroll
            for (int r = 0; r < 4; ++r) {
                size_t gi = ((size_t)b * C_ + ob + r) * HW + p0 + pl;
                out[gi] = (float)rx[r] + wbv[r] + sv * (acc[i][j][r] + b2v[r]);
            }
        }
    }
#undef ISSUE_A
#undef ISSUE_B
#undef STAGE_WRITE
#undef MFMA_TILE
}

// ---------------------------------------------------------------------------
extern "C" void kernel_launch(void* const* d_in, const int* in_sizes, int n_in,
                              void* d_out, int out_size, void* d_ws, size_t ws_size,
                              hipStream_t stream) {
    const float* x    = (const float*)d_in[0];
    const float* se   = (const float*)d_in[1];
    const float* wts  = (const float*)d_in[2];
    const float* wq_w = (const float*)d_in[3];
    const float* wq_b = (const float*)d_in[4];
    const float* wk_w = (const float*)d_in[5];
    // d_in[6] = wk_b: constant over softmax axis -> cancels, unused
    const float* wv_w = (const float*)d_in[7];
    const float* wv_b = (const float*)d_in[8];
    const float* wo_w = (const float*)d_in[9];
    const float* wo_b = (const float*)d_in[10];
    float* out = (float*)d_out;

    // workspace layout (<1MB)
    char* ws = (char*)d_ws;
    bf16*  Qkb = (bf16*) (ws + 0);          // 256KB  [16][16][512], rows 8..15 zero
    bf16*  W2  = (bf16*) (ws + 262144);     // 512KB
    float* b2  = (float*)(ws + 786432);     // 2KB

    k_pre   <<<dim3(512), dim3(512), 0, stream>>>(se, wts, wq_w, wq_b, wk_w,
                                                  wo_w, wv_w, wv_b, Qkb, W2, b2);
    k_fused <<<dim3(512), dim3(512), 0, stream>>>(x, W2, b2, wo_b, Qkb, out);
}